// Round 7
// baseline (366.331 us; speedup 1.0000x reference)
//
#include <hip/hip_runtime.h>
#include <hip/hip_bf16.h>
#include <math.h>

typedef __hip_bfloat16 bf16;
typedef __attribute__((ext_vector_type(8))) short short8;   // 8 x bf16 bits (4 VGPRs)
typedef __attribute__((ext_vector_type(4))) float f32x4;
typedef __attribute__((ext_vector_type(16))) float f32x16;

static constexpr int BB   = 2;
static constexpr int SS   = 2048;
static constexpr int DD   = 2048;
static constexpr int NH   = 16;
static constexpr int HDD  = 128;
static constexpr int LATD = 512;
static constexpr int MR   = BB * SS;   // 4096 token rows
static constexpr int QRS  = DD + LATD; // 2560: row stride of merged [Q | c_kv] buffer

#if __has_builtin(__builtin_amdgcn_exp2f)
#define EXP2F(x) __builtin_amdgcn_exp2f(x)
#else
#define EXP2F(x) exp2f(x)
#endif

__device__ __forceinline__ void async_cp16(const void* g, void* l) {
    __builtin_amdgcn_global_load_lds(
        (const __attribute__((address_space(1))) void*)g,
        (__attribute__((address_space(3))) void*)l, 16, 0, 0);
}

__device__ __forceinline__ unsigned short bf_bits(bf16 v) {
    union { bf16 b; unsigned short u; } cv; cv.b = v; return cv.u;
}

// ================= prep: cast x -> bf16 + transpose/cast Wq,Wdown,Wkup,Wvup =========
__global__ __launch_bounds__(256) void prep(
    const float* __restrict__ x, bf16* __restrict__ xb,
    const float* __restrict__ Wq, const float* __restrict__ Wdown,
    const float* __restrict__ Wkup, const float* __restrict__ Wvup,
    bf16* __restrict__ WqdT, bf16* __restrict__ WkvT) {
    __shared__ float tile[32][33];
    const int blk = blockIdx.x, tid = threadIdx.x;
    if (blk < 8192) {
        const int i = blk * 256 + tid;
        float4 v = ((const float4*)x)[i];
        ushort4 o;
        o.x = bf_bits(__float2bfloat16(v.x));
        o.y = bf_bits(__float2bfloat16(v.y));
        o.z = bf_bits(__float2bfloat16(v.z));
        o.w = bf_bits(__float2bfloat16(v.w));
        ((ushort4*)xb)[i] = o;
        return;
    }
    const float* in; bf16* out; int rows, cols, bx, by;
    if (blk < 12288) {
        const int l = blk - 8192;  in = Wq;    out = WqdT;
        rows = DD;   cols = DD;    bx = l & 63; by = l >> 6;
    } else if (blk < 13312) {
        const int l = blk - 12288; in = Wdown; out = WqdT + (size_t)DD * DD;
        rows = DD;   cols = LATD;  bx = l & 15; by = l >> 4;
    } else if (blk < 14336) {
        const int l = blk - 13312; in = Wkup;  out = WkvT;
        rows = LATD; cols = DD;    bx = l & 63; by = l >> 6;
    } else {
        const int l = blk - 14336; in = Wvup;  out = WkvT + (size_t)DD * LATD;
        rows = LATD; cols = DD;    bx = l & 63; by = l >> 6;
    }
    const int tx = tid & 31, ty = tid >> 5;
    const int c0 = bx * 32, r0 = by * 32;
    for (int i = 0; i < 32; i += 8)
        tile[ty + i][tx] = in[(size_t)(r0 + ty + i) * cols + c0 + tx];
    __syncthreads();
    for (int i = 0; i < 32; i += 8)
        out[(size_t)(c0 + ty + i) * rows + r0 + tx] =
            __float2bfloat16(tile[tx][ty + i]);
}

// ======== gemm256: 256x256 tile, BK=32, 8 waves (2Mx4N), 4-deep LDS ring =========
// T3+T4 structure: 2 phases per K-tile {ds_read frag subtile | stage 2 gload_lds |
// raw s_barrier | lgkmcnt(0) | setprio+16 MFMA | s_barrier}; counted vmcnt(8) once
// per tile (never 0 in hot loop) -> loads for 3 tiles stay in flight across
// barriers. Chunk-XOR swizzle (chunk^row&3) on stage-source + ds_read (v2b-proven
// involution) -> conflict-free frag reads. 128 KB LDS -> 1 block/CU, 2 waves/SIMD.
// Race-freedom: tile t+3 targets buf[(t-1)&3] whose last read retired before the
// barrier preceding this stage; per-wave vmcnt(8)-before-barrier => tile t+1
// resident block-wide before any wave reads it.
template <bool OUT_F32>
__global__ __launch_bounds__(512) void gemm256(
    const bf16* __restrict__ A, const bf16* __restrict__ Bt,
    void* __restrict__ Cout, int M, int N, int K, int lda, int ldb, int ldc) {
    __shared__ __align__(16) char smem[131072];   // 4 bufs x (A 16KB + B 16KB)
    const int tid  = threadIdx.x;
    const int lane = tid & 63, wave = tid >> 6;
    const int quad = lane >> 4, l16 = lane & 15;
    const int wm = wave >> 2, wn = wave & 3;      // 2M x 4N wave grid

    const int nx = N >> 8, ny = M >> 8;
    const int nwg = nx * ny;
    // XCD-chunked bijective remap + 4-row bands (each XCD works a compact patch)
    const int wg   = ((blockIdx.x & 7) * (nwg >> 3)) + (blockIdx.x >> 3);
    const int idx  = wg % (nx << 2);
    const int band = wg / (nx << 2);
    const int bcol = idx >> 2, brow = (band << 2) + (idx & 3);
    const int row0 = brow << 8, col0 = bcol << 8;

    const int NT = K >> 5;

    // stage one load-round l (0..3) of K-tile `tile` into its ring slot.
    // LDS linear: byte = slot*32768 + l*8192 + tid*16  (row rr = l*128 + tid>>2,
    // chunk tid&3); global source chunk = (tid&3)^(rr&3)  [inverse swizzle].
    auto stageL = [&](int tile, int l) {
        char* ldst = smem + (size_t)((tile & 3) * 32768 + l * 8192) + tid * 16;
        const int rr = l * 128 + (tid >> 2);
        const int sc = (tid & 3) ^ (rr & 3);
        if (l < 2)
            async_cp16(A + (size_t)(row0 + rr) * lda + tile * 32 + sc * 8, ldst);
        else
            async_cp16(Bt + (size_t)(col0 + (rr - 256)) * ldb + tile * 32 + sc * 8, ldst);
    };

    f32x4 acc[8][4];
#pragma unroll
    for (int m = 0; m < 8; ++m)
#pragma unroll
        for (int n = 0; n < 4; ++n)
#pragma unroll
            for (int r = 0; r < 4; ++r) acc[m][n][r] = 0.f;

    // prologue: stage tiles 0,1,2 (12 loads/thread); wait oldest 4 (tile 0)
    for (int tt = 0; tt < 3; ++tt)
#pragma unroll
        for (int l = 0; l < 4; ++l) stageL(tt, l);
    asm volatile("s_waitcnt vmcnt(8)" ::: "memory");
    __builtin_amdgcn_s_barrier();

    for (int t = 0; t < NT; ++t) {
        const char* base = smem + (size_t)(t & 3) * 32768;
        const bool more = (t + 3) < NT;

        // ---- phase A: read B-frags + A-frags m0..3; stage A-half of t+3 ----
        short8 bfr[4], afA[4];
#pragma unroll
        for (int n = 0; n < 4; ++n) {
            const int row = wn * 64 + n * 16 + l16;
            bfr[n] = *(const short8*)(base + 16384 + row * 64 + ((quad ^ (row & 3)) << 4));
        }
#pragma unroll
        for (int m = 0; m < 4; ++m) {
            const int row = wm * 128 + m * 16 + l16;
            afA[m] = *(const short8*)(base + row * 64 + ((quad ^ (row & 3)) << 4));
        }
        if (more) { stageL(t + 3, 0); stageL(t + 3, 1); }
        __builtin_amdgcn_s_barrier();
        __builtin_amdgcn_s_waitcnt(0xc07f);   // lgkmcnt(0)
        __builtin_amdgcn_s_setprio(1);
#pragma unroll
        for (int m = 0; m < 4; ++m)
#pragma unroll
            for (int n = 0; n < 4; ++n)
                acc[m][n] = __builtin_amdgcn_mfma_f32_16x16x32_bf16(
                    afA[m], bfr[n], acc[m][n], 0, 0, 0);
        __builtin_amdgcn_s_setprio(0);
        __builtin_amdgcn_s_barrier();

        // ---- phase B: read A-frags m4..7; stage B-half of t+3; counted vmcnt ----
        short8 afB[4];
#pragma unroll
        for (int m = 0; m < 4; ++m) {
            const int row = wm * 128 + (m + 4) * 16 + l16;
            afB[m] = *(const short8*)(base + row * 64 + ((quad ^ (row & 3)) << 4));
        }
        if (more) { stageL(t + 3, 2); stageL(t + 3, 3); }
        if (more) asm volatile("s_waitcnt vmcnt(8)" ::: "memory");
        else      asm volatile("s_waitcnt vmcnt(0)" ::: "memory");
        __builtin_amdgcn_s_barrier();
        __builtin_amdgcn_s_waitcnt(0xc07f);   // lgkmcnt(0)
        __builtin_amdgcn_s_setprio(1);
#pragma unroll
        for (int m = 0; m < 4; ++m)
#pragma unroll
            for (int n = 0; n < 4; ++n)
                acc[m + 4][n] = __builtin_amdgcn_mfma_f32_16x16x32_bf16(
                    afB[m], bfr[n], acc[m + 4][n], 0, 0, 0);
        __builtin_amdgcn_s_setprio(0);
        __builtin_amdgcn_s_barrier();
    }

    const int rbase = row0 + wm * 128 + quad * 4;
    const int cbase = col0 + wn * 64 + l16;
    if (OUT_F32) {
        float* C = (float*)Cout;
#pragma unroll
        for (int m = 0; m < 8; ++m)
#pragma unroll
            for (int n = 0; n < 4; ++n)
#pragma unroll
                for (int r = 0; r < 4; ++r)
                    C[(size_t)(rbase + m * 16 + r) * ldc + cbase + n * 16] = acc[m][n][r];
    } else {
        bf16* C = (bf16*)Cout;
#pragma unroll
        for (int m = 0; m < 8; ++m)
#pragma unroll
            for (int n = 0; n < 4; ++n)
#pragma unroll
                for (int r = 0; r < 4; ++r)
                    C[(size_t)(rbase + m * 16 + r) * ldc + cbase + n * 16] =
                        __float2bfloat16(acc[m][n][r]);
    }
}

// ====== tvrope: V pre-transpose + RoPE on K + Wo transpose, one launch ======
__global__ __launch_bounds__(256) void tvrope(
    bf16* __restrict__ KV, bf16* __restrict__ VT,
    const float* __restrict__ freqs,
    const float* __restrict__ Wo, bf16* __restrict__ WoT) {
    __shared__ __align__(16) char sm[64 * 74 * 2];   // also holds float[32][33]
    const int blk = blockIdx.x, tid = threadIdx.x;
    if (blk < 2048) {
        bf16 (*t)[74] = (bf16(*)[74])sm;
        const int bx = blk & 31, byy = (blk >> 5) & 1, bh = blk >> 6;
        const int s0 = bx * 64, d0 = byy * 64;
        const int b = bh >> 4, h = bh & 15;
        const bf16* src = KV + (size_t)b * SS * 4096 + 2048 + h * 128 + d0;
        for (int p = 0; p < 2; ++p) {
            const int s = p * 32 + (tid >> 3), dc = (tid & 7) * 8;
            short8 v = *(const short8*)(src + (size_t)(s0 + s) * 4096 + dc);
            const bf16* ve = (const bf16*)&v;
            for (int e = 0; e < 8; ++e) t[s][dc + e] = ve[e];
        }
        __syncthreads();
        bf16* dst = VT + ((size_t)bh * HDD + d0) * SS + s0;
        for (int p = 0; p < 2; ++p) {
            const int d = p * 32 + (tid >> 3), g = tid & 7;
            short8 v; bf16* ve = (bf16*)&v;
            for (int e = 0; e < 8; ++e) ve[e] = t[g * 8 + e][d];
            const int gp = g ^ (d & 7);
            *(short8*)(dst + (size_t)d * SS + gp * 8) = v;
        }
        return;
    }
    if (blk < 6144) {
        // RoPE on K only (Q's RoPE is fused into flash_attn's Q-fragment load)
        const int idx = (blk - 2048) * 256 + tid;
        const int pg  = idx & 15;
        const int h   = (idx >> 4) & (NH - 1);
        const int tok = idx >> 8;
        const int s   = tok & (SS - 1);
        const float4 f = *(const float4*)&freqs[s * 64 + pg * 4];
        const float fr[4] = {f.x, f.y, f.z, f.w};
        bf16* kp = KV + (size_t)tok * 4096 + h * HDD + pg * 8;
        short8 v = *(const short8*)kp;
        const bf16* ve = (const bf16*)&v;
        short8 o; bf16* oe = (bf16*)&o;
        for (int i = 0; i < 4; ++i) {
            const float cs = __cosf(fr[i]), sn = __sinf(fr[i]);
            const float t0 = __bfloat162float(ve[2 * i]);
            const float t1 = __bfloat162float(ve[2 * i + 1]);
            oe[2 * i]     = __float2bfloat16(t0 * cs - t1 * sn);
            oe[2 * i + 1] = __float2bfloat16(t0 * sn + t1 * cs);
        }
        *(short8*)kp = o;
        return;
    }
    {   // Wo transpose (WoT aliases WqdT: safe, QC gemm already retired in stream order)
        float (*tile)[33] = (float(*)[33])sm;
        const int l = blk - 6144;
        const int bx = l & 63, by = l >> 6;
        const int tx = tid & 31, ty = tid >> 5;
        const int c0 = bx * 32, r0 = by * 32;
        for (int i = 0; i < 32; i += 8)
            tile[ty + i][tx] = Wo[(size_t)(r0 + ty + i) * DD + c0 + tx];
        __syncthreads();
        for (int i = 0; i < 32; i += 8)
            WoT[(size_t)(c0 + ty + i) * DD + r0 + tx] =
                __float2bfloat16(tile[tx][ty + i]);
    }
}

// ------------- causal flash attention v2b (proven 74.4 us): 4 waves, 32x32 MFMA,
// swapped QK^T, in-register softmax. Cross-half exchanges via __shfl_xor;
// P->bf16 via scalar casts. Lane owns one q-row (col l32 of S^T). LDS 66 KB.
__global__ __launch_bounds__(256, 2) void flash_attn(
    const bf16* __restrict__ QC, const bf16* __restrict__ KV,
    const bf16* __restrict__ VTg, const float* __restrict__ freqs,
    bf16* __restrict__ O) {
    const int j = blockIdx.x;
    const int bh = (j >> 3) & 31, q3 = j & 7;
    const int qt = (j & 256) ? q3 : 15 - q3;
    const int h = bh & (NH - 1), b = bh >> 4;
    const int q0 = qt * 128;
    const int tid = threadIdx.x, lane = tid & 63, wave = tid >> 6;
    const int l32 = lane & 31, hi = lane >> 5;

    __shared__ __align__(16) char smem[66048];
    bf16*  KsB  = (bf16*)smem;              // [2][64*128]
    bf16*  VtB  = (bf16*)(smem + 32768);    // [2][128*64]
    float* RedS = (float*)(smem + 65536);   // [4][32]

    const bf16* Kb  = KV  + (size_t)b * SS * 4096 + h * HDD;
    const bf16* VTb = VTg + (size_t)bh * HDD * SS;

    // ---- Q B-frags (col=q=l32, k-elems d=dk*16+hi*8+e), RoPE+scale fused ----
    const float QS = 0.08838834764831845f * 1.4426950408889634f;  // 1/sqrt(HD)*log2e
    const int qrow = q0 + wave * 32 + l32;
    short8 qf[8];
    {
        const bf16* qp = QC + (size_t)(b * SS + qrow) * QRS + h * HDD;
#pragma unroll
        for (int dk = 0; dk < 8; ++dk) {
            short8 v = *(const short8*)(qp + dk * 16 + hi * 8);
            const float4 f = *(const float4*)&freqs[(size_t)qrow * 64 + dk * 8 + hi * 4];
            const float fr[4] = {f.x, f.y, f.z, f.w};
            const bf16* ve = (const bf16*)&v;
            bf16* oe = (bf16*)&qf[dk];
#pragma unroll
            for (int i2 = 0; i2 < 4; ++i2) {
                const float cs = __cosf(fr[i2]), sn = __sinf(fr[i2]);
                const float t0 = __bfloat162float(ve[2 * i2]);
                const float t1 = __bfloat162float(ve[2 * i2 + 1]);
                oe[2 * i2]     = __float2bfloat16((t0 * cs - t1 * sn) * QS);
                oe[2 * i2 + 1] = __float2bfloat16((t0 * sn + t1 * cs) * QS);
            }
        }
    }

    // ---- staging: K with inverse-swizzled source (linear LDS dest),
    //      V straight copy of pre-swizzled VTg rows ----
    auto stage = [&](int kt, int bufi) {
        const int k0 = kt * 64;
#pragma unroll
        for (int ii = 0; ii < 4; ++ii) {
            const int i = wave * 4 + ii;
            const int krow = 4 * i + (lane >> 4);
            const int csrc = (lane & 15) ^ (krow & 7);
            async_cp16(Kb + (size_t)(k0 + krow) * 4096 + csrc * 8,
                       KsB + bufi * 8192 + i * 512);
            const int d = 8 * i + (lane >> 3);
            async_cp16(VTb + (size_t)d * SS + k0 + (lane & 7) * 8,
                       VtB + bufi * 8192 + i * 512);
        }
    };

    f32x16 accO[4];
#pragma unroll
    for (int d = 0; d < 4; ++d)
#pragma unroll
        for (int r = 0; r < 16; ++r) accO[d][r] = 0.f;
    float m_r = -1e30f, l_r = 0.f;

    const int ktMax = 2 * qt + 1;
    const int qwb = q0 + wave * 32;      // wave's first q row

    stage(0, 0);
    for (int kt = 0; kt <= ktMax; ++kt) {
        const int k0 = kt * 64;
        __syncthreads();                    // drains stage kt; frees buf (kt+1)&1
        if (kt < ktMax) stage(kt + 1, (kt + 1) & 1);
        const int bi = kt & 1;

        if (k0 > qwb + 31) continue;        // tile entirely above diagonal (wave-uniform)

        // ---- S^T = K Q^T : lane holds 32 kv-scores for q-row l32 ----
        f32x16 st[2];
#pragma unroll
        for (int t = 0; t < 2; ++t)
#pragma unroll
            for (int r = 0; r < 16; ++r) st[t][r] = 0.f;
        __builtin_amdgcn_s_setprio(1);
#pragma unroll
        for (int dk = 0; dk < 8; ++dk)
#pragma unroll
            for (int t = 0; t < 2; ++t) {
                const int rd = t * 32 + l32;
                short8 kf = *(const short8*)
                    &KsB[bi * 8192 + rd * 128 + ((((dk << 1) | hi) ^ (rd & 7)) << 3)];
                st[t] = __builtin_amdgcn_mfma_f32_32x32x16_bf16(
                    kf, qf[dk], st[t], 0, 0, 0);
            }
        __builtin_amdgcn_s_setprio(0);

        float p[32];
#pragma unroll
        for (int t = 0; t < 2; ++t)
#pragma unroll
            for (int r = 0; r < 16; ++r) p[t * 16 + r] = st[t][r];

        // ---- causal mask (boundary tiles only; wave-uniform branch) ----
        if (k0 + 63 > qwb) {
#pragma unroll
            for (int t = 0; t < 2; ++t)
#pragma unroll
                for (int r = 0; r < 16; ++r) {
                    const int kv = k0 + t * 32 + (r & 3) + 8 * (r >> 2) + 4 * hi;
                    if (kv > qrow) p[t * 16 + r] = -1e30f;
                }
        }

        // ---- row max: lane-local tree + cross-half shfl ----
        float mt[16];
#pragma unroll
        for (int n = 0; n < 16; ++n) mt[n] = fmaxf(p[n], p[n + 16]);
#pragma unroll
        for (int n = 0; n < 8; ++n) mt[n] = fmaxf(mt[n], mt[n + 8]);
#pragma unroll
        for (int n = 0; n < 4; ++n) mt[n] = fmaxf(mt[n], mt[n + 4]);
        float mx = fmaxf(fmaxf(mt[0], mt[1]), fmaxf(mt[2], mt[3]));
        const float rmax = fmaxf(mx, __shfl_xor(mx, 32));

        // ---- defer-max (T13): rescale only when max grows > 2^8 ----
        const bool grow = rmax > m_r + 8.f;
        if (__any(grow)) {
            const float mnew = fmaxf(m_r, rmax);
            const float alpha = EXP2F(m_r - mnew);
            m_r = mnew;
            l_r *= alpha;
            RedS[wave * 32 + l32] = alpha;      // both halves write identical value
            __builtin_amdgcn_s_waitcnt(0xc07f); // lgkmcnt(0): own-wave writes visible
#pragma unroll
            for (int r = 0; r < 16; ++r) {
                const float av = RedS[wave * 32 + ((r & 3) + 8 * (r >> 2) + 4 * hi)];
#pragma unroll
                for (int d = 0; d < 4; ++d) accO[d][r] *= av;
            }
        }

        // ---- P = exp2(S - m); row sum (tree + cross-half shfl) ----
#pragma unroll
        for (int r = 0; r < 32; ++r) p[r] = EXP2F(p[r] - m_r);
        float sa[16];
#pragma unroll
        for (int n = 0; n < 16; ++n) sa[n] = p[n] + p[n + 16];
#pragma unroll
        for (int n = 0; n < 8; ++n) sa[n] += sa[n + 8];
#pragma unroll
        for (int n = 0; n < 4; ++n) sa[n] += sa[n + 4];
        float ps = (sa[0] + sa[1]) + (sa[2] + sa[3]);
        l_r += ps + __shfl_xor(ps, 32);

        // ---- P -> packed bf16 pairs (scalar casts; compiler emits cvt_pk) ----
        unsigned int pk[16];
#pragma unroll
        for (int n = 0; n < 16; ++n) {
            const unsigned int lo = bf_bits(__float2bfloat16(p[2 * n]));
            const unsigned int hl = bf_bits(__float2bfloat16(p[2 * n + 1]));
            pk[n] = lo | (hl << 16);
        }

        // ---- O += P V  (A-frags assembled via cross-half shfl) ----
#pragma unroll
        for (int m = 0; m < 4; ++m) {
            const int A0 = 4 * m;
            const unsigned int op0 = __shfl_xor(pk[A0 + 0], 32);
            const unsigned int op1 = __shfl_xor(pk[A0 + 1], 32);
            const unsigned int op2 = __shfl_xor(pk[A0 + 2], 32);
            const unsigned int op3 = __shfl_xor(pk[A0 + 3], 32);
            union { unsigned int w[4]; short8 s; } fr;
            fr.w[0] = hi ? op2 : pk[A0 + 0];
            fr.w[1] = hi ? op3 : pk[A0 + 1];
            fr.w[2] = hi ? pk[A0 + 2] : op0;
            fr.w[3] = hi ? pk[A0 + 3] : op1;
            __builtin_amdgcn_s_setprio(1);
#pragma unroll
            for (int db = 0; db < 4; ++db) {
                const int d = db * 32 + l32;
                short8 vf = *(const short8*)
                    &VtB[bi * 8192 + d * 64 + ((((m << 1) | hi) ^ (d & 7)) << 3)];
                accO[db] = __builtin_amdgcn_mfma_f32_32x32x16_bf16(
                    fr.s, vf, accO[db], 0, 0, 0);
            }
            __builtin_amdgcn_s_setprio(0);
        }
    }

    // ---- epilogue: 1/l per q-row, LDS bounce, coalesced bf16 stores ----
    const float invl = 1.f / l_r;
    RedS[wave * 32 + l32] = invl;
    __builtin_amdgcn_s_waitcnt(0xc07f);     // lgkmcnt(0): own-wave writes visible
    bf16* Ob = O + (size_t)b * SS * DD + h * HDD;
#pragma unroll
    for (int r = 0; r < 16; ++r) {
        const int row = (r & 3) + 8 * (r >> 2) + 4 * hi;
        const float iv = RedS[wave * 32 + row];
        const size_t ro = (size_t)(q0 + wave * 32 + row) * DD;
#pragma unroll
        for (int db = 0; db < 4; ++db)
            Ob[ro + db * 32 + l32] = __float2bfloat16(accO[db][r] * iv);
    }
}

extern "C" void kernel_launch(void* const* d_in, const int* in_sizes, int n_in,
                              void* d_out, int out_size, void* d_ws, size_t ws_size,
                              hipStream_t stream) {
    (void)in_sizes; (void)n_in; (void)out_size; (void)ws_size;
    const float* x     = (const float*)d_in[0];
    const float* freqs = (const float*)d_in[1];
    // d_in[2] = mask: exactly causal 0/-1e9 -> applied analytically in flash_attn
    const float* Wq    = (const float*)d_in[3];
    const float* Wdown = (const float*)d_in[4];
    const float* Wkup  = (const float*)d_in[5];
    const float* Wvup  = (const float*)d_in[6];
    const float* Wo    = (const float*)d_in[7];
    float* out = (float*)d_out;

    char* ws = (char*)d_ws;
    size_t off = 0;
    auto take = [&](size_t bytes) -> void* {
        void* p = ws + off;
        off += (bytes + 255) & ~(size_t)255;
        return p;
    };
    bf16* xb    = (bf16*)take((size_t)MR * DD * 2);         // 16.8 MB (later: attn)
    bf16* WqdT  = (bf16*)take((size_t)QRS * DD * 2);        // 10.5 MB (later: WoT)
    bf16* WkvT  = (bf16*)take((size_t)2 * DD * LATD * 2);   //  4.2 MB
    bf16* QC    = (bf16*)take((size_t)MR * QRS * 2);        // 21.0 MB [Q 2048 | ckv 512]
    bf16* KVb   = (bf16*)take((size_t)MR * 2 * DD * 2);     // 33.6 MB [tok][K | V]
    bf16* VTg   = (bf16*)take((size_t)BB * NH * HDD * SS * 2); // 16.8 MB (~103 MB total)
    bf16* attn  = xb;      // xb dead after QC gemm
    bf16* WoT   = WqdT;    // WqdT dead after QC gemm

    // cast x + all 4 early weight transposes in one launch
    prep<<<15360, 256, 0, stream>>>(x, xb, Wq, Wdown, Wkup, Wvup, WqdT, WkvT);

    // [Q | c_kv] = x [Wq | Wdown]   (M=4096, N=2560, K=2048) -> 160 blocks
    gemm256<false><<<(QRS / 256) * (MR / 256), 512, 0, stream>>>(
        xb, WqdT, QC, MR, QRS, DD, DD, DD, QRS);
    // [K | V] = c_kv [Wkup | Wvup]  (M=4096, N=4096, K=512) -> 256 blocks
    gemm256<false><<<(2 * DD / 256) * (MR / 256), 512, 0, stream>>>(
        QC + DD, WkvT, KVb, MR, 2 * DD, LATD, QRS, LATD, 2 * DD);

    // V transpose + K RoPE + Wo transpose, one launch
    tvrope<<<10240, 256, 0, stream>>>(KVb, VTg, freqs, Wo, WoT);

    flash_attn<<<512, 256, 0, stream>>>(QC, KVb, VTg, freqs, attn);

    // out = attn Wo (fp32 epilogue straight to d_out)  -> 128 blocks
    gemm256<true><<<(DD / 256) * (MR / 256), 512, 0, stream>>>(
        attn, WoT, out, MR, DD, DD, DD, DD, DD);
}

// Round 8
// 343.702 us; speedup vs baseline: 1.0658x; 1.0658x over previous
//
#include <hip/hip_runtime.h>
#include <hip/hip_bf16.h>
#include <math.h>

typedef __hip_bfloat16 bf16;
typedef __attribute__((ext_vector_type(8))) short short8;   // 8 x bf16 bits (4 VGPRs)
typedef __attribute__((ext_vector_type(4))) float f32x4;
typedef __attribute__((ext_vector_type(16))) float f32x16;

static constexpr int BB   = 2;
static constexpr int SS   = 2048;
static constexpr int DD   = 2048;
static constexpr int NH   = 16;
static constexpr int HDD  = 128;
static constexpr int LATD = 512;
static constexpr int MR   = BB * SS;   // 4096 token rows
static constexpr int QRS  = DD + LATD; // 2560: row stride of merged [Q | c_kv] buffer

#if __has_builtin(__builtin_amdgcn_exp2f)
#define EXP2F(x) __builtin_amdgcn_exp2f(x)
#else
#define EXP2F(x) exp2f(x)
#endif

__device__ __forceinline__ void async_cp16(const void* g, void* l) {
    __builtin_amdgcn_global_load_lds(
        (const __attribute__((address_space(1))) void*)g,
        (__attribute__((address_space(3))) void*)l, 16, 0, 0);
}

__device__ __forceinline__ unsigned short bf_bits(bf16 v) {
    union { bf16 b; unsigned short u; } cv; cv.b = v; return cv.u;
}

// ================= prep: cast x -> bf16 + transpose/cast Wq,Wdown,Wkup,Wvup =========
__global__ __launch_bounds__(256) void prep(
    const float* __restrict__ x, bf16* __restrict__ xb,
    const float* __restrict__ Wq, const float* __restrict__ Wdown,
    const float* __restrict__ Wkup, const float* __restrict__ Wvup,
    bf16* __restrict__ WqdT, bf16* __restrict__ WkvT) {
    __shared__ float tile[32][33];
    const int blk = blockIdx.x, tid = threadIdx.x;
    if (blk < 8192) {
        const int i = blk * 256 + tid;
        float4 v = ((const float4*)x)[i];
        ushort4 o;
        o.x = bf_bits(__float2bfloat16(v.x));
        o.y = bf_bits(__float2bfloat16(v.y));
        o.z = bf_bits(__float2bfloat16(v.z));
        o.w = bf_bits(__float2bfloat16(v.w));
        ((ushort4*)xb)[i] = o;
        return;
    }
    const float* in; bf16* out; int rows, cols, bx, by;
    if (blk < 12288) {
        const int l = blk - 8192;  in = Wq;    out = WqdT;
        rows = DD;   cols = DD;    bx = l & 63; by = l >> 6;
    } else if (blk < 13312) {
        const int l = blk - 12288; in = Wdown; out = WqdT + (size_t)DD * DD;
        rows = DD;   cols = LATD;  bx = l & 15; by = l >> 4;
    } else if (blk < 14336) {
        const int l = blk - 13312; in = Wkup;  out = WkvT;
        rows = LATD; cols = DD;    bx = l & 63; by = l >> 6;
    } else {
        const int l = blk - 14336; in = Wvup;  out = WkvT + (size_t)DD * LATD;
        rows = LATD; cols = DD;    bx = l & 63; by = l >> 6;
    }
    const int tx = tid & 31, ty = tid >> 5;
    const int c0 = bx * 32, r0 = by * 32;
    for (int i = 0; i < 32; i += 8)
        tile[ty + i][tx] = in[(size_t)(r0 + ty + i) * cols + c0 + tx];
    __syncthreads();
    for (int i = 0; i < 32; i += 8)
        out[(size_t)(c0 + ty + i) * rows + r0 + tx] =
            __float2bfloat16(tile[tx][ty + i]);
}

// ------- double-buffered GEMM: C[M][N] = A[M][K(lda)] * Bt[N][K(ldb)]^T -------
// 1D grid; XCD-chunked bijective remap + group-of-8-rows supertile (R6 winner).
// ROPE: fuse K-RoPE into the epilogue (GEMM2's K-half, block-uniform col0<2048):
// pairs (d,d+1) are adjacent lanes (col parity == l16 parity) -> shfl_xor(v,1),
// applied on f32 acc before the bf16 cast.
template <bool OUT_F32, bool ROPE>
__global__ __launch_bounds__(256) void gemm_bt(
    const bf16* __restrict__ A, const bf16* __restrict__ Bt,
    void* __restrict__ Cout, int M, int N, int K, int lda, int ldb, int ldc,
    const float* __restrict__ freqs) {
    __shared__ bf16 As[2][128 * 32];
    __shared__ bf16 Bs[2][128 * 32];
    const int tid  = threadIdx.x;
    const int lane = tid & 63, wave = tid >> 6;
    const int quad = lane >> 4, l16 = lane & 15;

    const int nx = N >> 7, ny = M >> 7;
    const int nwg = nx * ny;
    // XCD-contiguous chunk (blocks round-robin XCDs by blockIdx%8)
    const int wg  = ((blockIdx.x & 7) * (nwg >> 3)) + (blockIdx.x >> 3);
    // grouped supertile: sweep 8 rows, then next column
    const int nig = nx << 3;                 // blocks per 8-row group
    const int brow = ((wg / nig) << 3) + (wg & 7);
    const int bcol = (wg % nig) >> 3;
    const int row0 = brow * 128, col0 = bcol * 128;

    const int wm = (wave >> 1) * 64, wn = (wave & 1) * 64;
    const int srow = lane >> 2;
    const int scol = (lane & 3) * 8;

    f32x4 acc[4][4];
    for (int i = 0; i < 4; ++i)
        for (int j = 0; j < 4; ++j)
            for (int r = 0; r < 4; ++r) acc[i][j][r] = 0.f;

    auto stage = [&](int k0, int bufi) {
        for (int c = 0; c < 2; ++c) {
            const int chunk = wave * 2 + c;
            const int r = chunk * 16 + srow;
            async_cp16(A  + (size_t)(row0 + r) * lda + k0 + scol, &As[bufi][chunk * 512]);
            async_cp16(Bt + (size_t)(col0 + r) * ldb + k0 + scol, &Bs[bufi][chunk * 512]);
        }
    };

    const int nk = K / 32;
    stage(0, 0);
    for (int ki = 0; ki < nk; ++ki) {
        __syncthreads();                    // drains stage ki; frees buf (ki+1)&1
        if (ki + 1 < nk) stage((ki + 1) * 32, (ki + 1) & 1);
        const int bi = ki & 1;
        short8 af[4], bfr[4];
        for (int t = 0; t < 4; ++t) {
            af[t]  = *(const short8*)&As[bi][(wm + t * 16 + l16) * 32 + quad * 8];
            bfr[t] = *(const short8*)&Bs[bi][(wn + t * 16 + l16) * 32 + quad * 8];
        }
        for (int i = 0; i < 4; ++i)
            for (int j = 0; j < 4; ++j)
                acc[i][j] = __builtin_amdgcn_mfma_f32_16x16x32_bf16(
                    af[i], bfr[j], acc[i][j], 0, 0, 0);
    }

    const int rbase = row0 + wm + quad * 4;
    const int cbase = col0 + wn + l16;
    if (OUT_F32) {
        float* C = (float*)Cout;
        for (int i = 0; i < 4; ++i)
            for (int j = 0; j < 4; ++j)
                for (int r = 0; r < 4; ++r)
                    C[(size_t)(rbase + i * 16 + r) * ldc + cbase + j * 16] = acc[i][j][r];
    } else if (ROPE && col0 < 2048) {
        // K-half of GEMM2: RoPE fused on f32 acc (partner value from lane^1)
        bf16* C = (bf16*)Cout;
        for (int i = 0; i < 4; ++i)
            for (int r = 0; r < 4; ++r) {
                const int s = (rbase + i * 16 + r) & (SS - 1);
                const float* fro = freqs + (size_t)s * 64;
                for (int j = 0; j < 4; ++j) {
                    const int d = wn + j * 16 + l16;     // col&127 (no wrap)
                    const float f = fro[d >> 1];
                    const float cs = __cosf(f), sn = __sinf(f);
                    const float v  = acc[i][j][r];
                    const float vp = __shfl_xor(v, 1);
                    const float o  = (l16 & 1) ? (vp * sn + v * cs)
                                               : (v * cs - vp * sn);
                    C[(size_t)(rbase + i * 16 + r) * ldc + cbase + j * 16] =
                        __float2bfloat16(o);
                }
            }
    } else {
        bf16* C = (bf16*)Cout;
        for (int i = 0; i < 4; ++i)
            for (int j = 0; j < 4; ++j)
                for (int r = 0; r < 4; ++r)
                    C[(size_t)(rbase + i * 16 + r) * ldc + cbase + j * 16] =
                        __float2bfloat16(acc[i][j][r]);
    }
}

// ====== tvrope: V pre-transpose + Wo transpose, one launch (K-RoPE now in GEMM2) ======
__global__ __launch_bounds__(256) void tvrope(
    bf16* __restrict__ KV, bf16* __restrict__ VT,
    const float* __restrict__ Wo, bf16* __restrict__ WoT) {
    __shared__ __align__(16) char sm[64 * 74 * 2];   // also holds float[32][33]
    const int blk = blockIdx.x, tid = threadIdx.x;
    if (blk < 2048) {
        bf16 (*t)[74] = (bf16(*)[74])sm;
        const int bx = blk & 31, byy = (blk >> 5) & 1, bh = blk >> 6;
        const int s0 = bx * 64, d0 = byy * 64;
        const int b = bh >> 4, h = bh & 15;
        const bf16* src = KV + (size_t)b * SS * 4096 + 2048 + h * 128 + d0;
        for (int p = 0; p < 2; ++p) {
            const int s = p * 32 + (tid >> 3), dc = (tid & 7) * 8;
            short8 v = *(const short8*)(src + (size_t)(s0 + s) * 4096 + dc);
            const bf16* ve = (const bf16*)&v;
            for (int e = 0; e < 8; ++e) t[s][dc + e] = ve[e];
        }
        __syncthreads();
        bf16* dst = VT + ((size_t)bh * HDD + d0) * SS + s0;
        for (int p = 0; p < 2; ++p) {
            const int d = p * 32 + (tid >> 3), g = tid & 7;
            short8 v; bf16* ve = (bf16*)&v;
            for (int e = 0; e < 8; ++e) ve[e] = t[g * 8 + e][d];
            const int gp = g ^ (d & 7);
            *(short8*)(dst + (size_t)d * SS + gp * 8) = v;
        }
        return;
    }
    {   // Wo transpose (WoT aliases WqdT: safe, QC gemm already retired in stream order)
        float (*tile)[33] = (float(*)[33])sm;
        const int l = blk - 2048;
        const int bx = l & 63, by = l >> 6;
        const int tx = tid & 31, ty = tid >> 5;
        const int c0 = bx * 32, r0 = by * 32;
        for (int i = 0; i < 32; i += 8)
            tile[ty + i][tx] = Wo[(size_t)(r0 + ty + i) * DD + c0 + tx];
        __syncthreads();
        for (int i = 0; i < 32; i += 8)
            WoT[(size_t)(c0 + ty + i) * DD + r0 + tx] =
                __float2bfloat16(tile[tx][ty + i]);
    }
}

// ------------- causal flash attention v2b (proven 74.4 us): 4 waves, 32x32 MFMA,
// swapped QK^T, in-register softmax. Cross-half exchanges via __shfl_xor;
// P->bf16 via scalar casts. Lane owns one q-row (col l32 of S^T). LDS 66 KB.
__global__ __launch_bounds__(256, 2) void flash_attn(
    const bf16* __restrict__ QC, const bf16* __restrict__ KV,
    const bf16* __restrict__ VTg, const float* __restrict__ freqs,
    bf16* __restrict__ O) {
    const int j = blockIdx.x;
    const int bh = (j >> 3) & 31, q3 = j & 7;
    const int qt = (j & 256) ? q3 : 15 - q3;
    const int h = bh & (NH - 1), b = bh >> 4;
    const int q0 = qt * 128;
    const int tid = threadIdx.x, lane = tid & 63, wave = tid >> 6;
    const int l32 = lane & 31, hi = lane >> 5;

    __shared__ __align__(16) char smem[66048];
    bf16*  KsB  = (bf16*)smem;              // [2][64*128]
    bf16*  VtB  = (bf16*)(smem + 32768);    // [2][128*64]
    float* RedS = (float*)(smem + 65536);   // [4][32]

    const bf16* Kb  = KV  + (size_t)b * SS * 4096 + h * HDD;
    const bf16* VTb = VTg + (size_t)bh * HDD * SS;

    // ---- Q B-frags (col=q=l32, k-elems d=dk*16+hi*8+e), RoPE+scale fused ----
    const float QS = 0.08838834764831845f * 1.4426950408889634f;  // 1/sqrt(HD)*log2e
    const int qrow = q0 + wave * 32 + l32;
    short8 qf[8];
    {
        const bf16* qp = QC + (size_t)(b * SS + qrow) * QRS + h * HDD;
#pragma unroll
        for (int dk = 0; dk < 8; ++dk) {
            short8 v = *(const short8*)(qp + dk * 16 + hi * 8);
            const float4 f = *(const float4*)&freqs[(size_t)qrow * 64 + dk * 8 + hi * 4];
            const float fr[4] = {f.x, f.y, f.z, f.w};
            const bf16* ve = (const bf16*)&v;
            bf16* oe = (bf16*)&qf[dk];
#pragma unroll
            for (int i2 = 0; i2 < 4; ++i2) {
                const float cs = __cosf(fr[i2]), sn = __sinf(fr[i2]);
                const float t0 = __bfloat162float(ve[2 * i2]);
                const float t1 = __bfloat162float(ve[2 * i2 + 1]);
                oe[2 * i2]     = __float2bfloat16((t0 * cs - t1 * sn) * QS);
                oe[2 * i2 + 1] = __float2bfloat16((t0 * sn + t1 * cs) * QS);
            }
        }
    }

    // ---- staging: K with inverse-swizzled source (linear LDS dest),
    //      V straight copy of pre-swizzled VTg rows ----
    auto stage = [&](int kt, int bufi) {
        const int k0 = kt * 64;
#pragma unroll
        for (int ii = 0; ii < 4; ++ii) {
            const int i = wave * 4 + ii;
            const int krow = 4 * i + (lane >> 4);
            const int csrc = (lane & 15) ^ (krow & 7);
            async_cp16(Kb + (size_t)(k0 + krow) * 4096 + csrc * 8,
                       KsB + bufi * 8192 + i * 512);
            const int d = 8 * i + (lane >> 3);
            async_cp16(VTb + (size_t)d * SS + k0 + (lane & 7) * 8,
                       VtB + bufi * 8192 + i * 512);
        }
    };

    f32x16 accO[4];
#pragma unroll
    for (int d = 0; d < 4; ++d)
#pragma unroll
        for (int r = 0; r < 16; ++r) accO[d][r] = 0.f;
    float m_r = -1e30f, l_r = 0.f;

    const int ktMax = 2 * qt + 1;
    const int qwb = q0 + wave * 32;      // wave's first q row

    stage(0, 0);
    for (int kt = 0; kt <= ktMax; ++kt) {
        const int k0 = kt * 64;
        __syncthreads();                    // drains stage kt; frees buf (kt+1)&1
        if (kt < ktMax) stage(kt + 1, (kt + 1) & 1);
        const int bi = kt & 1;

        if (k0 > qwb + 31) continue;        // tile entirely above diagonal (wave-uniform)

        // ---- S^T = K Q^T : lane holds 32 kv-scores for q-row l32 ----
        f32x16 st[2];
#pragma unroll
        for (int t = 0; t < 2; ++t)
#pragma unroll
            for (int r = 0; r < 16; ++r) st[t][r] = 0.f;
        __builtin_amdgcn_s_setprio(1);
#pragma unroll
        for (int dk = 0; dk < 8; ++dk)
#pragma unroll
            for (int t = 0; t < 2; ++t) {
                const int rd = t * 32 + l32;
                short8 kf = *(const short8*)
                    &KsB[bi * 8192 + rd * 128 + ((((dk << 1) | hi) ^ (rd & 7)) << 3)];
                st[t] = __builtin_amdgcn_mfma_f32_32x32x16_bf16(
                    kf, qf[dk], st[t], 0, 0, 0);
            }
        __builtin_amdgcn_s_setprio(0);

        float p[32];
#pragma unroll
        for (int t = 0; t < 2; ++t)
#pragma unroll
            for (int r = 0; r < 16; ++r) p[t * 16 + r] = st[t][r];

        // ---- causal mask (boundary tiles only; wave-uniform branch) ----
        if (k0 + 63 > qwb) {
#pragma unroll
            for (int t = 0; t < 2; ++t)
#pragma unroll
                for (int r = 0; r < 16; ++r) {
                    const int kv = k0 + t * 32 + (r & 3) + 8 * (r >> 2) + 4 * hi;
                    if (kv > qrow) p[t * 16 + r] = -1e30f;
                }
        }

        // ---- row max: lane-local tree + cross-half shfl ----
        float mt[16];
#pragma unroll
        for (int n = 0; n < 16; ++n) mt[n] = fmaxf(p[n], p[n + 16]);
#pragma unroll
        for (int n = 0; n < 8; ++n) mt[n] = fmaxf(mt[n], mt[n + 8]);
#pragma unroll
        for (int n = 0; n < 4; ++n) mt[n] = fmaxf(mt[n], mt[n + 4]);
        float mx = fmaxf(fmaxf(mt[0], mt[1]), fmaxf(mt[2], mt[3]));
        const float rmax = fmaxf(mx, __shfl_xor(mx, 32));

        // ---- defer-max (T13): rescale only when max grows > 2^8 ----
        const bool grow = rmax > m_r + 8.f;
        if (__any(grow)) {
            const float mnew = fmaxf(m_r, rmax);
            const float alpha = EXP2F(m_r - mnew);
            m_r = mnew;
            l_r *= alpha;
            RedS[wave * 32 + l32] = alpha;      // both halves write identical value
            __builtin_amdgcn_s_waitcnt(0xc07f); // lgkmcnt(0): own-wave writes visible
#pragma unroll
            for (int r = 0; r < 16; ++r) {
                const float av = RedS[wave * 32 + ((r & 3) + 8 * (r >> 2) + 4 * hi)];
#pragma unroll
                for (int d = 0; d < 4; ++d) accO[d][r] *= av;
            }
        }

        // ---- P = exp2(S - m); row sum (tree + cross-half shfl) ----
#pragma unroll
        for (int r = 0; r < 32; ++r) p[r] = EXP2F(p[r] - m_r);
        float sa[16];
#pragma unroll
        for (int n = 0; n < 16; ++n) sa[n] = p[n] + p[n + 16];
#pragma unroll
        for (int n = 0; n < 8; ++n) sa[n] += sa[n + 8];
#pragma unroll
        for (int n = 0; n < 4; ++n) sa[n] += sa[n + 4];
        float ps = (sa[0] + sa[1]) + (sa[2] + sa[3]);
        l_r += ps + __shfl_xor(ps, 32);

        // ---- P -> packed bf16 pairs (scalar casts; compiler emits cvt_pk) ----
        unsigned int pk[16];
#pragma unroll
        for (int n = 0; n < 16; ++n) {
            const unsigned int lo = bf_bits(__float2bfloat16(p[2 * n]));
            const unsigned int hl = bf_bits(__float2bfloat16(p[2 * n + 1]));
            pk[n] = lo | (hl << 16);
        }

        // ---- O += P V  (A-frags assembled via cross-half shfl) ----
#pragma unroll
        for (int m = 0; m < 4; ++m) {
            const int A0 = 4 * m;
            const unsigned int op0 = __shfl_xor(pk[A0 + 0], 32);
            const unsigned int op1 = __shfl_xor(pk[A0 + 1], 32);
            const unsigned int op2 = __shfl_xor(pk[A0 + 2], 32);
            const unsigned int op3 = __shfl_xor(pk[A0 + 3], 32);
            union { unsigned int w[4]; short8 s; } fr;
            fr.w[0] = hi ? op2 : pk[A0 + 0];
            fr.w[1] = hi ? op3 : pk[A0 + 1];
            fr.w[2] = hi ? pk[A0 + 2] : op0;
            fr.w[3] = hi ? pk[A0 + 3] : op1;
            __builtin_amdgcn_s_setprio(1);
#pragma unroll
            for (int db = 0; db < 4; ++db) {
                const int d = db * 32 + l32;
                short8 vf = *(const short8*)
                    &VtB[bi * 8192 + d * 64 + ((((m << 1) | hi) ^ (d & 7)) << 3)];
                accO[db] = __builtin_amdgcn_mfma_f32_32x32x16_bf16(
                    fr.s, vf, accO[db], 0, 0, 0);
            }
            __builtin_amdgcn_s_setprio(0);
        }
    }

    // ---- epilogue: 1/l per q-row, LDS bounce, coalesced bf16 stores ----
    const float invl = 1.f / l_r;
    RedS[wave * 32 + l32] = invl;
    __builtin_amdgcn_s_waitcnt(0xc07f);     // lgkmcnt(0): own-wave writes visible
    bf16* Ob = O + (size_t)b * SS * DD + h * HDD;
#pragma unroll
    for (int r = 0; r < 16; ++r) {
        const int row = (r & 3) + 8 * (r >> 2) + 4 * hi;
        const float iv = RedS[wave * 32 + row];
        const size_t ro = (size_t)(q0 + wave * 32 + row) * DD;
#pragma unroll
        for (int db = 0; db < 4; ++db)
            Ob[ro + db * 32 + l32] = __float2bfloat16(accO[db][r] * iv);
    }
}

extern "C" void kernel_launch(void* const* d_in, const int* in_sizes, int n_in,
                              void* d_out, int out_size, void* d_ws, size_t ws_size,
                              hipStream_t stream) {
    (void)in_sizes; (void)n_in; (void)out_size; (void)ws_size;
    const float* x     = (const float*)d_in[0];
    const float* freqs = (const float*)d_in[1];
    // d_in[2] = mask: exactly causal 0/-1e9 -> applied analytically in flash_attn
    const float* Wq    = (const float*)d_in[3];
    const float* Wdown = (const float*)d_in[4];
    const float* Wkup  = (const float*)d_in[5];
    const float* Wvup  = (const float*)d_in[6];
    const float* Wo    = (const float*)d_in[7];
    float* out = (float*)d_out;

    char* ws = (char*)d_ws;
    size_t off = 0;
    auto take = [&](size_t bytes) -> void* {
        void* p = ws + off;
        off += (bytes + 255) & ~(size_t)255;
        return p;
    };
    bf16* xb    = (bf16*)take((size_t)MR * DD * 2);         // 16.8 MB (later: attn)
    bf16* WqdT  = (bf16*)take((size_t)QRS * DD * 2);        // 10.5 MB (later: WoT)
    bf16* WkvT  = (bf16*)take((size_t)2 * DD * LATD * 2);   //  4.2 MB
    bf16* QC    = (bf16*)take((size_t)MR * QRS * 2);        // 21.0 MB [Q 2048 | ckv 512]
    bf16* KVb   = (bf16*)take((size_t)MR * 2 * DD * 2);     // 33.6 MB [tok][K | V]
    bf16* VTg   = (bf16*)take((size_t)BB * NH * HDD * SS * 2); // 16.8 MB (~103 MB total)
    bf16* attn  = xb;      // xb dead after QC gemm
    bf16* WoT   = WqdT;    // WqdT dead after QC gemm

    // cast x + all 4 early weight transposes in one launch
    prep<<<15360, 256, 0, stream>>>(x, xb, Wq, Wdown, Wkup, Wvup, WqdT, WkvT);

    // [Q | c_kv] = x [Wq | Wdown]   (M=4096, N=2560, K=2048) -> 640 blocks
    gemm_bt<false, false><<<(QRS / 128) * (MR / 128), 256, 0, stream>>>(
        xb, WqdT, QC, MR, QRS, DD, DD, DD, QRS, nullptr);
    // [K | V] = c_kv [Wkup | Wvup]  (M=4096, N=4096, K=512) -> 1024 blocks
    // K-half gets RoPE fused in the epilogue.
    gemm_bt<false, true><<<(2 * DD / 128) * (MR / 128), 256, 0, stream>>>(
        QC + DD, WkvT, KVb, MR, 2 * DD, LATD, QRS, LATD, 2 * DD, freqs);

    // V transpose + Wo transpose, one launch
    tvrope<<<6144, 256, 0, stream>>>(KVb, VTg, Wo, WoT);

    flash_attn<<<512, 256, 0, stream>>>(QC, KVb, VTg, freqs, attn);

    // out = attn Wo (fp32 epilogue straight to d_out)  -> 512 blocks
    gemm_bt<true, false><<<(DD / 128) * (MR / 128), 256, 0, stream>>>(
        attn, WoT, out, MR, DD, DD, DD, DD, DD, nullptr);
}